// Round 9
// baseline (252.864 us; speedup 1.0000x reference)
//
#include <hip/hip_runtime.h>
#include <hip/hip_bf16.h>

#define HID 128
#define EXP 3
#define TOP 4
#define OUTC 64
#define SLOTC 64                     // per-node slot capacity (Poisson(16): P(deg>64) ~ 3e-22)

typedef __bf16 bf16x8 __attribute__((ext_vector_type(8)));
typedef float f32x16 __attribute__((ext_vector_type(16)));
typedef float f32x2 __attribute__((ext_vector_type(2)));

#define GLDS_STRIDE 272              // staging: 128 bf16 = 256B + 16B pad
#define OUT_STRIDE 132               // out tile: 128 fp32 + 4 pad dwords

// fp8 e4m3 helpers (gfx950 HW cvt, OCP format; encode RNE)
__device__ __forceinline__ unsigned int pack4_fp8(float a, float b, float c, float d) {
    int v = 0;
    v = __builtin_amdgcn_cvt_pk_fp8_f32(a, b, v, false);   // bytes 0,1
    v = __builtin_amdgcn_cvt_pk_fp8_f32(c, d, v, true);    // bytes 2,3
    return (unsigned int)v;
}

__device__ __forceinline__ void unpack4_fp8(unsigned int v, float* out) {
    f32x2 lo = __builtin_amdgcn_cvt_pk_f32_fp8((int)v, false);
    f32x2 hi = __builtin_amdgcn_cvt_pk_f32_fp8((int)v, true);
    out[0] = lo[0]; out[1] = lo[1]; out[2] = hi[0]; out[3] = hi[1];
}

// accumulate 16 fp8 channels (one uint4), unweighted (rows are pre-scaled by dinv[src])
__device__ __forceinline__ void add16_fp8(uint4 a, float* acc) {
    unsigned int q[4] = {a.x, a.y, a.z, a.w};
#pragma unroll
    for (int k = 0; k < 4; ++k) {
        float f[4];
        unpack4_fp8(q[k], f);
#pragma unroll
        for (int j = 0; j < 4; ++j) acc[k * 4 + j] += f[j];
    }
}

// ---------------- mega0: slotted fill (single atomic pass) + gates + gstart + pack_w ----------------

__global__ __launch_bounds__(256) void mega0_kernel(
        const int* __restrict__ src, const int* __restrict__ dst,
        int* __restrict__ cnt, int* __restrict__ slots, int E,
        const float* __restrict__ tf, const float* __restrict__ Wg0,
        const float* __restrict__ Wg1, float* __restrict__ gates,
        const int* __restrict__ batch, int* __restrict__ gstart,
        const float* __restrict__ W0, const float* __restrict__ W1,
        __bf16* __restrict__ ph0, __bf16* __restrict__ ph1,
        int N, int G, int nFill, int nGate) {
    int b = blockIdx.x;
    int t = threadIdx.x;

    if (b < nFill) {                        // XCD-sliced slotted fill, 8 edges/thread
        int slice = b & 7;
        int base = (b >> 3) * 2048 + t * 8;
        if (base < E) {
            if (base + 8 <= E) {
                int4 d0 = *(const int4*)(dst + base);
                int4 d1 = *(const int4*)(dst + base + 4);
                int dv[8] = {d0.x, d0.y, d0.z, d0.w, d1.x, d1.y, d1.z, d1.w};
#pragma unroll
                for (int k = 0; k < 8; ++k) {
                    int d = dv[k];
                    if (((d >> 6) & 7) != slice) continue;
                    int s = src[base + k];
                    int p = atomicAdd(&cnt[d], 1);
                    if (p < SLOTC) slots[(size_t)d * SLOTC + p] = s;
                }
            } else {
                for (int i = base; i < E; ++i) {
                    int d = dst[i];
                    if (((d >> 6) & 7) != slice) continue;
                    int s = src[i];
                    int p = atomicAdd(&cnt[d], 1);
                    if (p < SLOTC) slots[(size_t)d * SLOTC + p] = s;
                }
            }
        }
        return;
    }
    b -= nFill;
    if (b < nGate) {                        // gate softmax for both layers
        int n = b * 256 + t;
        if (n >= N) return;
        float4 tv = *(const float4*)(tf + (size_t)n * TOP);
        const float* Wg[2] = {Wg0, Wg1};
#pragma unroll
        for (int l = 0; l < 2; ++l) {
            float lg[EXP];
#pragma unroll
            for (int e = 0; e < EXP; ++e) {
                const float* w = Wg[l] + e * TOP;
                lg[e] = (tv.x * w[0] + tv.y * w[1] + tv.z * w[2] + tv.w * w[3]) * (1.0f / 101.0f);
            }
            float m = fmaxf(lg[0], fmaxf(lg[1], lg[2]));
            float e0 = expf(lg[0] - m), e1 = expf(lg[1] - m), e2 = expf(lg[2] - m);
            float inv = 1.0f / (e0 + e1 + e2);
            gates[n * 6 + l * 3 + 0] = e0 * inv;
            gates[n * 6 + l * 3 + 1] = e1 * inv;
            gates[n * 6 + l * 3 + 2] = e2 * inv;
        }
        return;
    }
    b -= nGate;
    if (b == 0) {                           // gstart binary search
        int g = t;
        if (g > G) return;
        if (g == G) { gstart[G] = N; return; }
        int lo = 0, hi = N;
        while (lo < hi) {
            int mid = (lo + hi) >> 1;
            if (batch[mid] < g) lo = mid + 1; else hi = mid;
        }
        gstart[g] = lo;
        return;
    }
    b -= 1;
    // pack_w: 48 blocks x (4 jobs of 64 lanes)
    int job = b * 4 + (t >> 6);
    if (job >= 192) return;
    int l = t & 63;
    int layer = job / 96;
    int rem = job % 96;
    int e = rem / 32;
    int s = (rem % 32) / 4;
    int c = rem % 4;
    const float* W = layer ? W1 : W0;
    __bf16* ph = layer ? ph1 : ph0;
    size_t dstbase = (size_t)((((e * 8 + s) * 4 + c) * 64 + l)) * 8;
    int kbase = s * 16 + (l >> 5) * 8;
    int ncol = c * 32 + (l & 31);
#pragma unroll
    for (int j = 0; j < 8; ++j) {
        float w = W[(size_t)e * (HID * HID) + (size_t)(kbase + j) * HID + ncol];
        ph[dstbase + j] = (__bf16)w;
    }
}

// ---------------- prep2: x -> fp8 pre-scaled by dinv (needs cnt, so runs after mega0) ----------------

__global__ __launch_bounds__(256) void prep2_kernel(const float* __restrict__ x,
                                                    unsigned int* __restrict__ x8,
                                                    const int* __restrict__ cnt, int N) {
    int i = blockIdx.x * 256 + threadIdx.x;    // one thread = 16 channels of node i>>3
    int total16 = N * (HID / 16);
    if (i >= total16) return;
    int n = i >> 3;
    float dn = rsqrtf((float)cnt[n] + 1.0f);
    const float4* xp = (const float4*)x + (size_t)i * 4;
    float4 v0 = xp[0], v1 = xp[1], v2 = xp[2], v3 = xp[3];
    uint4 o;
    o.x = pack4_fp8(v0.x * dn, v0.y * dn, v0.z * dn, v0.w * dn);
    o.y = pack4_fp8(v1.x * dn, v1.y * dn, v1.z * dn, v1.w * dn);
    o.z = pack4_fp8(v2.x * dn, v2.y * dn, v2.z * dn, v2.w * dn);
    o.w = pack4_fp8(v3.x * dn, v3.y * dn, v3.z * dn, v3.w * dn);
    ((uint4*)x8)[i] = o;
}

// ---------------- agg: channel-half aggregation (L2-resident gather table) ----------------
// One dispatch per 64-channel half: table footprint N*64B = 3.2MB < 4MB L2/XCD.
// 64 nodes/block, 4 thr/node x 16 channels; per edge the node's 4 threads read one 64B
// sector. No LDS, no barriers -> high occupancy. Output bf16 agg[N][128].

__global__ __launch_bounds__(256) void agg_kernel(
        const unsigned char* __restrict__ h8in,
        const int* __restrict__ cnt, const int* __restrict__ slots,
        __bf16* __restrict__ agg, int half, int N) {
    int tid = threadIdx.x;
    int r = tid >> 2;
    int part = tid & 3;                 // 16B chunk within the 64B half
    int n = blockIdx.x * 64 + r;
    if (n >= N) return;

    const unsigned char* hb = h8in + half * 64 + part * 16;
    int degt = cnt[n];
    int deg = min(degt, SLOTC);
    float dn = rsqrtf((float)degt + 1.0f);

    float acc[16];
    // self contribution: h'[n] (already dinv[n]-scaled)
    uint4 v = *(const uint4*)(hb + (size_t)n * HID);
    {
        unsigned int q[4] = {v.x, v.y, v.z, v.w};
#pragma unroll
        for (int k = 0; k < 4; ++k) {
            float f[4];
            unpack4_fp8(q[k], f);
#pragma unroll
            for (int j = 0; j < 4; ++j) acc[k * 4 + j] = f[j];
        }
    }
    const int* sl = slots + (size_t)n * SLOTC;
    int i = 0;
    if (deg >= 4) {
        int4 sv = *(const int4*)(sl);
        for (; i + 4 <= deg; i += 4) {
            uint4 a0 = *(const uint4*)(hb + (size_t)sv.x * HID);
            uint4 a1 = *(const uint4*)(hb + (size_t)sv.y * HID);
            uint4 a2 = *(const uint4*)(hb + (size_t)sv.z * HID);
            uint4 a3 = *(const uint4*)(hb + (size_t)sv.w * HID);
            sv = *(const int4*)(sl + i + 4);   // prefetch next quad (overread in-bounds)
            add16_fp8(a0, acc);
            add16_fp8(a1, acc);
            add16_fp8(a2, acc);
            add16_fp8(a3, acc);
        }
    }
    for (; i < deg; ++i) {
        uint4 a0 = *(const uint4*)(hb + (size_t)sl[i] * HID);
        add16_fp8(a0, acc);
    }
#pragma unroll
    for (int j = 0; j < 16; ++j) acc[j] *= dn;

    __bf16* dp = agg + (size_t)n * HID + half * 64 + part * 16;
    bf16x8 h0, h1;
#pragma unroll
    for (int j = 0; j < 8; ++j) { h0[j] = (__bf16)acc[j]; h1[j] = (__bf16)acc[8 + j]; }
    *(bf16x8*)dp = h0;
    *(bf16x8*)(dp + 8) = h1;
}

// ---------------- MFMA 3-expert GEMM + relu + gate (reads bf16 agg) ----------------
// 512 thr, 64 rows, 8 waves x one 32x32 tile (proven r5/r6 shape).

__global__ __launch_bounds__(512, 4) void gemm_kernel(
        const __bf16* __restrict__ agg,
        const __bf16* __restrict__ wpkh,
        const float* __restrict__ bias, const float* __restrict__ gates, int gate_off,
        const int* __restrict__ cnt,
        unsigned char* __restrict__ hout8,
        const int* __restrict__ batch, float* __restrict__ pooled, int N) {
    __shared__ char lds[64 * OUT_STRIDE * 4];   // 33792 B; staging uses first 17408
    int tid = threadIdx.x;
    int row0 = blockIdx.x * 64;

#pragma unroll
    for (int it = 0; it < 2; ++it) {
        int id = tid + it * 512;
        int r = id >> 4;
        int c = id & 15;
        int gr = row0 + r;
        float4 vh = make_float4(0.f, 0.f, 0.f, 0.f);
        if (gr < N) vh = ((const float4*)agg)[(size_t)gr * 16 + c];
        *(float4*)(lds + r * GLDS_STRIDE + c * 16) = vh;
    }
    __syncthreads();

    int lane = tid & 63;
    int wave = tid >> 6;                // 0..7
    int m = lane & 31;
    int g = lane >> 5;
    int rhalf = wave & 1;
    int cq = wave >> 1;                 // 0..3
    const char* arow = lds + (rhalf * 32 + m) * GLDS_STRIDE + g * 16;
    int rowbase = row0 + rhalf * 32 + 4 * g;

    float F[16];
#pragma unroll
    for (int r = 0; r < 16; ++r) F[r] = 0.f;

    for (int e = 0; e < EXP; ++e) {
        f32x16 acc;
#pragma unroll
        for (int r = 0; r < 16; ++r) acc[r] = 0.f;

#pragma unroll
        for (int s = 0; s < 8; ++s) {
            bf16x8 Ah = *(const bf16x8*)(arow + s * 32);
            bf16x8 Bh = *(const bf16x8*)(wpkh + (size_t)(((e * 8 + s) * 4 + cq) * 64 + lane) * 8);
            acc = __builtin_amdgcn_mfma_f32_32x32x16_bf16(Ah, Bh, acc, 0, 0, 0);
        }
        float gt[16];
#pragma unroll
        for (int r = 0; r < 16; ++r) {
            int rr = rowbase + (r & 3) + 8 * (r >> 2);
            gt[r] = (rr < N) ? gates[(size_t)rr * 6 + gate_off + e] : 0.f;
        }
        float bb = bias[e * HID + cq * 32 + m];
#pragma unroll
        for (int r = 0; r < 16; ++r)
            F[r] += gt[r] * fmaxf(acc[r] + bb, 0.f);
    }

    // ---- fragments -> LDS out-tile ----
    __syncthreads();
    float* lds32 = (float*)lds;
    {
        int colg = cq * 32 + m;
#pragma unroll
        for (int r = 0; r < 16; ++r) {
            int lr = rhalf * 32 + 4 * g + (r & 3) + 8 * (r >> 2);
            lds32[lr * OUT_STRIDE + colg] = F[r];
        }
    }
    __syncthreads();

    if (hout8) {
        // write h1 pre-scaled by dinv[row] so layer 2 aggregates without per-edge weights
#pragma unroll
        for (int it = 0; it < 4; ++it) {
            int id = tid + it * 512;
            int r = id >> 5;
            int c4 = id & 31;
            int gr = row0 + r;
            if (gr < N) {
                float dr = rsqrtf((float)cnt[gr] + 1.0f);
                const float* src = &lds32[r * OUT_STRIDE + c4 * 4];
                *(unsigned int*)(hout8 + (size_t)gr * HID + c4 * 4) =
                    pack4_fp8(src[0] * dr, src[1] * dr, src[2] * dr, src[3] * dr);
            }
        }
    }
    if (pooled) {
        int col = tid & 127;
        int rbase = (tid >> 7) * 16;
        int cur = -1;
        float acc = 0.f;
        for (int r = 0; r < 16; ++r) {
            int gr = row0 + rbase + r;
            if (gr >= N) break;
            int gb = batch[gr];
            if (gb != cur) {
                if (cur >= 0) atomicAdd(&pooled[cur * HID + col], acc);
                acc = 0.f;
                cur = gb;
            }
            acc += lds32[(rbase + r) * OUT_STRIDE + col];
        }
        if (cur >= 0) atomicAdd(&pooled[cur * HID + col], acc);
    }
}

// ---------------- final ----------------

__global__ __launch_bounds__(64) void final_kernel(const float* __restrict__ pooled,
                                                   const int* __restrict__ gstart,
                                                   const float* __restrict__ Wf,
                                                   const float* __restrict__ bf,
                                                   float* __restrict__ out) {
    __shared__ float ps[HID];
    int g = blockIdx.x;
    int o = threadIdx.x;
    float invc = 1.0f / fmaxf((float)(gstart[g + 1] - gstart[g]), 1.0f);
    ps[o] = pooled[g * HID + o] * invc;
    ps[o + 64] = pooled[g * HID + o + 64] * invc;
    __syncthreads();
    float acc = bf[o];
#pragma unroll 8
    for (int k = 0; k < HID; ++k) acc = fmaf(ps[k], Wf[k * OUTC + o], acc);
    out[g * OUTC + o] = acc;
}

// ---------------- launch ----------------

extern "C" void kernel_launch(void* const* d_in, const int* in_sizes, int n_in,
                              void* d_out, int out_size, void* d_ws, size_t ws_size,
                              hipStream_t stream) {
    const float* x   = (const float*)d_in[0];
    const float* tf  = (const float*)d_in[1];
    const int*   ei  = (const int*)d_in[2];
    const int*   bat = (const int*)d_in[3];
    const float* W0  = (const float*)d_in[4];
    const float* b0  = (const float*)d_in[5];
    const float* Wg0 = (const float*)d_in[6];
    const float* W1  = (const float*)d_in[7];
    const float* b1  = (const float*)d_in[8];
    const float* Wg1 = (const float*)d_in[9];
    const float* Wf  = (const float*)d_in[10];
    const float* bf  = (const float*)d_in[11];
    float* out = (float*)d_out;

    const int N = in_sizes[0] / HID;       // 50000
    const int E = in_sizes[2] / 2;         // 800000
    const int G = out_size / OUTC;         // 64

    char* p = (char*)d_ws;
    auto alloc = [&](size_t bytes) -> void* {
        void* r = (void*)p;
        p += (bytes + 255) & ~(size_t)255;
        return r;
    };
    // cnt and pooled adjacent -> single memset covers both
    int*           cnt    = (int*)alloc((size_t)N * 4);
    float*         pooled = (float*)alloc((size_t)G * HID * 4);
    int*           slots  = (int*)alloc((size_t)N * SLOTC * 4);       // 12.8 MB
    float*         gates  = (float*)alloc((size_t)N * 6 * 4);
    unsigned char* x8     = (unsigned char*)alloc((size_t)N * HID);   // layer-1 fp8 input (pre-scaled)
    unsigned char* h8b    = (unsigned char*)alloc((size_t)N * HID);   // layer-1 out / layer-2 in (pre-scaled)
    __bf16*        aggbuf = (__bf16*)alloc((size_t)N * HID * 2);      // bf16 aggregation buffer
    int*           gstart = (int*)alloc((size_t)(G + 1) * 4);
    __bf16*        wpkh0  = (__bf16*)alloc((size_t)EXP * HID * HID * 2);
    __bf16*        wpkh1  = (__bf16*)alloc((size_t)EXP * HID * HID * 2);

    const int* src = ei;
    const int* dst = ei + E;

    size_t zlen = (size_t)((char*)pooled - (char*)cnt) + (size_t)G * HID * 4;
    hipMemsetAsync(cnt, 0, zlen, stream);

    const int nFill = ((E + 2047) / 2048) * 8;
    const int nGate = (N + 255) / 256;
    const int megaBlocks = nFill + nGate + 1 + 48;

    mega0_kernel<<<megaBlocks, 256, 0, stream>>>(src, dst, cnt, slots, E,
                                                 tf, Wg0, Wg1, gates,
                                                 bat, gstart,
                                                 W0, W1, wpkh0, wpkh1,
                                                 N, G, nFill, nGate);

    const int prepBlocks = (N * (HID / 16) + 255) / 256;
    prep2_kernel<<<prepBlocks, 256, 0, stream>>>(x, (unsigned int*)x8, cnt, N);

    const int nbAgg = (N + 63) / 64;

    // layer 1: channel-half aggregation (two dispatches = phase barrier for L2 residency)
    agg_kernel<<<nbAgg, 256, 0, stream>>>(x8, cnt, slots, aggbuf, 0, N);
    agg_kernel<<<nbAgg, 256, 0, stream>>>(x8, cnt, slots, aggbuf, 1, N);
    gemm_kernel<<<nbAgg, 512, 0, stream>>>(aggbuf, wpkh0, b0, gates, 0, cnt,
                                           h8b, nullptr, nullptr, N);

    // layer 2
    agg_kernel<<<nbAgg, 256, 0, stream>>>(h8b, cnt, slots, aggbuf, 0, N);
    agg_kernel<<<nbAgg, 256, 0, stream>>>(h8b, cnt, slots, aggbuf, 1, N);
    gemm_kernel<<<nbAgg, 512, 0, stream>>>(aggbuf, wpkh1, b1, gates, 3, cnt,
                                           nullptr, bat, pooled, N);

    final_kernel<<<G, 64, 0, stream>>>(pooled, gstart, Wf, bf, out);
}

// Round 10
// 217.631 us; speedup vs baseline: 1.1619x; 1.1619x over previous
//
#include <hip/hip_runtime.h>
#include <hip/hip_bf16.h>

#define HID 128
#define EXP 3
#define TOP 4
#define OUTC 64
#define SLOTC 64                     // per-node slot capacity (Poisson(16): P(deg>64) ~ 3e-22)

typedef __bf16 bf16x8 __attribute__((ext_vector_type(8)));
typedef float f32x16 __attribute__((ext_vector_type(16)));
typedef float f32x2 __attribute__((ext_vector_type(2)));

#define GLDS_STRIDE 272              // staging: 128 bf16 = 256B + 16B pad
#define OUT_STRIDE 132               // out tile: 128 fp32 + 4 pad dwords
#define SLOT_LDS_OFF (64 * GLDS_STRIDE)   // 17408; slot cache 16384B; total 33792

// fp8 e4m3 helpers (gfx950 HW cvt, OCP format; encode RNE)
__device__ __forceinline__ unsigned int pack4_fp8(float a, float b, float c, float d) {
    int v = 0;
    v = __builtin_amdgcn_cvt_pk_fp8_f32(a, b, v, false);   // bytes 0,1
    v = __builtin_amdgcn_cvt_pk_fp8_f32(c, d, v, true);    // bytes 2,3
    return (unsigned int)v;
}

__device__ __forceinline__ void unpack4_fp8(unsigned int v, float* out) {
    f32x2 lo = __builtin_amdgcn_cvt_pk_f32_fp8((int)v, false);
    f32x2 hi = __builtin_amdgcn_cvt_pk_f32_fp8((int)v, true);
    out[0] = lo[0]; out[1] = lo[1]; out[2] = hi[0]; out[3] = hi[1];
}

// accumulate 16 fp8 channels (one uint4), unweighted (rows are pre-scaled by dinv[src])
__device__ __forceinline__ void add16_fp8(uint4 a, float* acc) {
    unsigned int q[4] = {a.x, a.y, a.z, a.w};
#pragma unroll
    for (int k = 0; k < 4; ++k) {
        float f[4];
        unpack4_fp8(q[k], f);
#pragma unroll
        for (int j = 0; j < 4; ++j) acc[k * 4 + j] += f[j];
    }
}

// ---------------- mega0: slotted fill (single atomic pass) + gates + gstart + pack_w ----------------

__global__ __launch_bounds__(256) void mega0_kernel(
        const int* __restrict__ src, const int* __restrict__ dst,
        int* __restrict__ cnt, int* __restrict__ slots, int E,
        const float* __restrict__ tf, const float* __restrict__ Wg0,
        const float* __restrict__ Wg1, float* __restrict__ gates,
        const int* __restrict__ batch, int* __restrict__ gstart,
        const float* __restrict__ W0, const float* __restrict__ W1,
        __bf16* __restrict__ ph0, __bf16* __restrict__ ph1,
        int N, int G, int nFill, int nGate) {
    int b = blockIdx.x;
    int t = threadIdx.x;

    if (b < nFill) {                        // XCD-sliced slotted fill, 8 edges/thread
        int slice = b & 7;
        int base = (b >> 3) * 2048 + t * 8;
        if (base < E) {
            if (base + 8 <= E) {
                int4 d0 = *(const int4*)(dst + base);
                int4 d1 = *(const int4*)(dst + base + 4);
                int dv[8] = {d0.x, d0.y, d0.z, d0.w, d1.x, d1.y, d1.z, d1.w};
#pragma unroll
                for (int k = 0; k < 8; ++k) {
                    int d = dv[k];
                    if (((d >> 6) & 7) != slice) continue;
                    int s = src[base + k];
                    int p = atomicAdd(&cnt[d], 1);
                    if (p < SLOTC) slots[(size_t)d * SLOTC + p] = s;
                }
            } else {
                for (int i = base; i < E; ++i) {
                    int d = dst[i];
                    if (((d >> 6) & 7) != slice) continue;
                    int s = src[i];
                    int p = atomicAdd(&cnt[d], 1);
                    if (p < SLOTC) slots[(size_t)d * SLOTC + p] = s;
                }
            }
        }
        return;
    }
    b -= nFill;
    if (b < nGate) {                        // gate softmax for both layers
        int n = b * 256 + t;
        if (n >= N) return;
        float4 tv = *(const float4*)(tf + (size_t)n * TOP);
        const float* Wg[2] = {Wg0, Wg1};
#pragma unroll
        for (int l = 0; l < 2; ++l) {
            float lg[EXP];
#pragma unroll
            for (int e = 0; e < EXP; ++e) {
                const float* w = Wg[l] + e * TOP;
                lg[e] = (tv.x * w[0] + tv.y * w[1] + tv.z * w[2] + tv.w * w[3]) * (1.0f / 101.0f);
            }
            float m = fmaxf(lg[0], fmaxf(lg[1], lg[2]));
            float e0 = expf(lg[0] - m), e1 = expf(lg[1] - m), e2 = expf(lg[2] - m);
            float inv = 1.0f / (e0 + e1 + e2);
            gates[n * 6 + l * 3 + 0] = e0 * inv;
            gates[n * 6 + l * 3 + 1] = e1 * inv;
            gates[n * 6 + l * 3 + 2] = e2 * inv;
        }
        return;
    }
    b -= nGate;
    if (b == 0) {                           // gstart binary search
        int g = t;
        if (g > G) return;
        if (g == G) { gstart[G] = N; return; }
        int lo = 0, hi = N;
        while (lo < hi) {
            int mid = (lo + hi) >> 1;
            if (batch[mid] < g) lo = mid + 1; else hi = mid;
        }
        gstart[g] = lo;
        return;
    }
    b -= 1;
    // pack_w: 48 blocks x (4 jobs of 64 lanes)
    int job = b * 4 + (t >> 6);
    if (job >= 192) return;
    int l = t & 63;
    int layer = job / 96;
    int rem = job % 96;
    int e = rem / 32;
    int s = (rem % 32) / 4;
    int c = rem % 4;
    const float* W = layer ? W1 : W0;
    __bf16* ph = layer ? ph1 : ph0;
    size_t dstbase = (size_t)((((e * 8 + s) * 4 + c) * 64 + l)) * 8;
    int kbase = s * 16 + (l >> 5) * 8;
    int ncol = c * 32 + (l & 31);
#pragma unroll
    for (int j = 0; j < 8; ++j) {
        float w = W[(size_t)e * (HID * HID) + (size_t)(kbase + j) * HID + ncol];
        ph[dstbase + j] = (__bf16)w;
    }
}

// ---------------- prep2: x -> fp8 pre-scaled by dinv (needs cnt, so runs after mega0) ----------------

__global__ __launch_bounds__(256) void prep2_kernel(const float* __restrict__ x,
                                                    unsigned int* __restrict__ x8,
                                                    const int* __restrict__ cnt, int N) {
    int i = blockIdx.x * 256 + threadIdx.x;    // one thread = 16 channels of node i>>3
    int total16 = N * (HID / 16);
    if (i >= total16) return;
    int n = i >> 3;
    float dn = rsqrtf((float)cnt[n] + 1.0f);
    const float4* xp = (const float4*)x + (size_t)i * 4;
    float4 v0 = xp[0], v1 = xp[1], v2 = xp[2], v3 = xp[3];
    uint4 o;
    o.x = pack4_fp8(v0.x * dn, v0.y * dn, v0.z * dn, v0.w * dn);
    o.y = pack4_fp8(v1.x * dn, v1.y * dn, v1.z * dn, v1.w * dn);
    o.z = pack4_fp8(v2.x * dn, v2.y * dn, v2.z * dn, v2.w * dn);
    o.w = pack4_fp8(v3.x * dn, v3.y * dn, v3.z * dn, v3.w * dn);
    ((uint4*)x8)[i] = o;
}

// ---------------- fused aggregate + MFMA 3-expert GEMM + relu + gate ----------------
// rows in h8in are pre-scaled by dinv[src]; agg[d] = dinv[d] * (h'[d] + sum h'[s]).
// phase 0: cooperative slot-table load (64 nodes x 64 slots = 16KB) into LDS.
// phase 1: 8 thr/node x 16 ch; slot quads from LDS (short dep chain), 4-deep gathers.
// phase 2: MFMA 32x32x16, 8 waves x 1 tile.

__global__ __launch_bounds__(512, 4) void fused_layer_kernel(
        const unsigned char* __restrict__ h8in,
        const __bf16* __restrict__ wpkh,
        const float* __restrict__ bias, const float* __restrict__ gates, int gate_off,
        const int* __restrict__ cnt, const int* __restrict__ slots,
        unsigned char* __restrict__ hout8,
        const int* __restrict__ batch, float* __restrict__ pooled, int N) {
    __shared__ char lds[64 * OUT_STRIDE * 4];   // 33792 B: 17408 staging + 16384 slot cache
    int tid = threadIdx.x;
    int row0 = blockIdx.x * 64;

    // ---- phase 0: slot table -> LDS (coalesced; rows >= N carry garbage, never used) ----
    {
        uint4* sdst = (uint4*)(lds + SLOT_LDS_OFF);
        const uint4* ssrc = (const uint4*)(slots + (size_t)row0 * SLOTC);
        sdst[tid] = ssrc[tid];
        sdst[tid + 512] = ssrc[tid + 512];
    }
    __syncthreads();

    // ---- phase 1: aggregate into staging LDS ----
    {
        int r = tid >> 3;
        int part = tid & 7;                 // 16-channel slice
        int n = row0 + r;
        float acc[16];
#pragma unroll
        for (int j = 0; j < 16; ++j) acc[j] = 0.f;
        if (n < N) {
            const unsigned char* hb = h8in + part * 16;
            int degt = cnt[n];
            int deg = min(degt, SLOTC);
            float dn = rsqrtf((float)degt + 1.0f);
            // self contribution: h'[n] (already dinv[n]-scaled)
            uint4 v = *(const uint4*)(hb + (size_t)n * HID);
            {
                unsigned int q[4] = {v.x, v.y, v.z, v.w};
#pragma unroll
                for (int k = 0; k < 4; ++k) {
                    float f[4];
                    unpack4_fp8(q[k], f);
#pragma unroll
                    for (int j = 0; j < 4; ++j) acc[k * 4 + j] = f[j];
                }
            }
            const int* sl = (const int*)(lds + SLOT_LDS_OFF) + r * SLOTC;
            int i = 0;
            for (; i + 4 <= deg; i += 4) {
                int4 sv = *(const int4*)(sl + i);          // LDS read, ~short latency
                uint4 a0 = *(const uint4*)(hb + (size_t)sv.x * HID);
                uint4 a1 = *(const uint4*)(hb + (size_t)sv.y * HID);
                uint4 a2 = *(const uint4*)(hb + (size_t)sv.z * HID);
                uint4 a3 = *(const uint4*)(hb + (size_t)sv.w * HID);
                add16_fp8(a0, acc);
                add16_fp8(a1, acc);
                add16_fp8(a2, acc);
                add16_fp8(a3, acc);
            }
            for (; i < deg; ++i) {
                uint4 a0 = *(const uint4*)(hb + (size_t)sl[i] * HID);
                add16_fp8(a0, acc);
            }
            // final node-side scale
#pragma unroll
            for (int j = 0; j < 16; ++j) acc[j] *= dn;
        }
        char* drow = lds + r * GLDS_STRIDE + part * 32;
        bf16x8 h0, h1;
#pragma unroll
        for (int j = 0; j < 8; ++j) { h0[j] = (__bf16)acc[j]; h1[j] = (__bf16)acc[8 + j]; }
        *(bf16x8*)drow = h0;
        *(bf16x8*)(drow + 16) = h1;
    }
    __syncthreads();

    // ---- phase 2: MFMA expert GEMM, 8 waves x 1 tile (rhalf x col-quarter) ----
    int lane = tid & 63;
    int wave = tid >> 6;                // 0..7
    int m = lane & 31;
    int g = lane >> 5;
    int rhalf = wave & 1;
    int cq = wave >> 1;                 // 0..3
    const char* arow = lds + (rhalf * 32 + m) * GLDS_STRIDE + g * 16;
    int rowbase = row0 + rhalf * 32 + 4 * g;

    float F[16];
#pragma unroll
    for (int r = 0; r < 16; ++r) F[r] = 0.f;

    for (int e = 0; e < EXP; ++e) {
        f32x16 acc;
#pragma unroll
        for (int r = 0; r < 16; ++r) acc[r] = 0.f;

#pragma unroll
        for (int s = 0; s < 8; ++s) {
            bf16x8 Ah = *(const bf16x8*)(arow + s * 32);
            bf16x8 Bh = *(const bf16x8*)(wpkh + (size_t)(((e * 8 + s) * 4 + cq) * 64 + lane) * 8);
            acc = __builtin_amdgcn_mfma_f32_32x32x16_bf16(Ah, Bh, acc, 0, 0, 0);
        }
        float gt[16];
#pragma unroll
        for (int r = 0; r < 16; ++r) {
            int rr = rowbase + (r & 3) + 8 * (r >> 2);
            gt[r] = (rr < N) ? gates[(size_t)rr * 6 + gate_off + e] : 0.f;
        }
        float bb = bias[e * HID + cq * 32 + m];
#pragma unroll
        for (int r = 0; r < 16; ++r)
            F[r] += gt[r] * fmaxf(acc[r] + bb, 0.f);
    }

    // ---- fragments -> LDS out-tile ----
    __syncthreads();
    float* lds32 = (float*)lds;
    {
        int colg = cq * 32 + m;
#pragma unroll
        for (int r = 0; r < 16; ++r) {
            int lr = rhalf * 32 + 4 * g + (r & 3) + 8 * (r >> 2);
            lds32[lr * OUT_STRIDE + colg] = F[r];
        }
    }
    __syncthreads();

    if (hout8) {
        // write h1 pre-scaled by dinv[row] so layer 2 aggregates without per-edge weights
#pragma unroll
        for (int it = 0; it < 4; ++it) {
            int id = tid + it * 512;
            int r = id >> 5;
            int c4 = id & 31;
            int gr = row0 + r;
            if (gr < N) {
                float dr = rsqrtf((float)cnt[gr] + 1.0f);
                const float* src = &lds32[r * OUT_STRIDE + c4 * 4];
                *(unsigned int*)(hout8 + (size_t)gr * HID + c4 * 4) =
                    pack4_fp8(src[0] * dr, src[1] * dr, src[2] * dr, src[3] * dr);
            }
        }
    }
    if (pooled) {
        int col = tid & 127;
        int rbase = (tid >> 7) * 16;
        int cur = -1;
        float acc = 0.f;
        for (int r = 0; r < 16; ++r) {
            int gr = row0 + rbase + r;
            if (gr >= N) break;
            int gb = batch[gr];
            if (gb != cur) {
                if (cur >= 0) atomicAdd(&pooled[cur * HID + col], acc);
                acc = 0.f;
                cur = gb;
            }
            acc += lds32[(rbase + r) * OUT_STRIDE + col];
        }
        if (cur >= 0) atomicAdd(&pooled[cur * HID + col], acc);
    }
}

// ---------------- final ----------------

__global__ __launch_bounds__(64) void final_kernel(const float* __restrict__ pooled,
                                                   const int* __restrict__ gstart,
                                                   const float* __restrict__ Wf,
                                                   const float* __restrict__ bf,
                                                   float* __restrict__ out) {
    __shared__ float ps[HID];
    int g = blockIdx.x;
    int o = threadIdx.x;
    float invc = 1.0f / fmaxf((float)(gstart[g + 1] - gstart[g]), 1.0f);
    ps[o] = pooled[g * HID + o] * invc;
    ps[o + 64] = pooled[g * HID + o + 64] * invc;
    __syncthreads();
    float acc = bf[o];
#pragma unroll 8
    for (int k = 0; k < HID; ++k) acc = fmaf(ps[k], Wf[k * OUTC + o], acc);
    out[g * OUTC + o] = acc;
}

// ---------------- launch ----------------

extern "C" void kernel_launch(void* const* d_in, const int* in_sizes, int n_in,
                              void* d_out, int out_size, void* d_ws, size_t ws_size,
                              hipStream_t stream) {
    const float* x   = (const float*)d_in[0];
    const float* tf  = (const float*)d_in[1];
    const int*   ei  = (const int*)d_in[2];
    const int*   bat = (const int*)d_in[3];
    const float* W0  = (const float*)d_in[4];
    const float* b0  = (const float*)d_in[5];
    const float* Wg0 = (const float*)d_in[6];
    const float* W1  = (const float*)d_in[7];
    const float* b1  = (const float*)d_in[8];
    const float* Wg1 = (const float*)d_in[9];
    const float* Wf  = (const float*)d_in[10];
    const float* bf  = (const float*)d_in[11];
    float* out = (float*)d_out;

    const int N = in_sizes[0] / HID;       // 50000
    const int E = in_sizes[2] / 2;         // 800000
    const int G = out_size / OUTC;         // 64

    char* p = (char*)d_ws;
    auto alloc = [&](size_t bytes) -> void* {
        void* r = (void*)p;
        p += (bytes + 255) & ~(size_t)255;
        return r;
    };
    // cnt and pooled adjacent -> single memset covers both
    int*           cnt    = (int*)alloc((size_t)N * 4);
    float*         pooled = (float*)alloc((size_t)G * HID * 4);
    int*           slots  = (int*)alloc((size_t)(N + 64) * SLOTC * 4); // +64 rows tail pad
    float*         gates  = (float*)alloc((size_t)N * 6 * 4);
    unsigned char* x8     = (unsigned char*)alloc((size_t)N * HID);   // layer-1 fp8 input (pre-scaled)
    unsigned char* h8b    = (unsigned char*)alloc((size_t)N * HID);   // layer-1 out / layer-2 in (pre-scaled)
    int*           gstart = (int*)alloc((size_t)(G + 1) * 4);
    __bf16*        wpkh0  = (__bf16*)alloc((size_t)EXP * HID * HID * 2);
    __bf16*        wpkh1  = (__bf16*)alloc((size_t)EXP * HID * HID * 2);

    const int* src = ei;
    const int* dst = ei + E;

    size_t zlen = (size_t)((char*)pooled - (char*)cnt) + (size_t)G * HID * 4;
    hipMemsetAsync(cnt, 0, zlen, stream);

    const int nFill = ((E + 2047) / 2048) * 8;
    const int nGate = (N + 255) / 256;
    const int megaBlocks = nFill + nGate + 1 + 48;

    mega0_kernel<<<megaBlocks, 256, 0, stream>>>(src, dst, cnt, slots, E,
                                                 tf, Wg0, Wg1, gates,
                                                 bat, gstart,
                                                 W0, W1, wpkh0, wpkh1,
                                                 N, G, nFill, nGate);

    const int prepBlocks = (N * (HID / 16) + 255) / 256;
    prep2_kernel<<<prepBlocks, 256, 0, stream>>>(x, (unsigned int*)x8, cnt, N);

    int gemm_blocks = (N + 63) / 64;

    // layer 1: fused aggregate(x8) + GEMM -> fp8 h (pre-scaled)
    fused_layer_kernel<<<gemm_blocks, 512, 0, stream>>>(x8, wpkh0, b0, gates, 0,
                                                        cnt, slots,
                                                        h8b, nullptr, nullptr, N);
    // layer 2: fused aggregate(h8b) + GEMM -> pooled
    fused_layer_kernel<<<gemm_blocks, 512, 0, stream>>>(h8b, wpkh1, b1, gates, 3,
                                                        cnt, slots,
                                                        nullptr, bat, pooled, N);

    final_kernel<<<G, 64, 0, stream>>>(pooled, gstart, Wf, bf, out);
}

// Round 11
// 217.191 us; speedup vs baseline: 1.1643x; 1.0020x over previous
//
#include <hip/hip_runtime.h>
#include <hip/hip_bf16.h>

#define HID 128
#define EXP 3
#define TOP 4
#define OUTC 64
#define SLOTC 64                     // per-node slot capacity (Poisson(16): P(deg>64) ~ 3e-22)

typedef __bf16 bf16x8 __attribute__((ext_vector_type(8)));
typedef float f32x16 __attribute__((ext_vector_type(16)));
typedef float f32x2 __attribute__((ext_vector_type(2)));

#define GLDS_STRIDE 272              // staging: 128 bf16 = 256B + 16B pad
#define OUT_STRIDE 132               // out tile: 128 fp32 + 4 pad dwords
#define SLOT_LDS_OFF (64 * GLDS_STRIDE)   // 17408; slot cache 16384B; total 33792

// fp8 e4m3 helpers (gfx950 HW cvt, OCP format; encode RNE)
__device__ __forceinline__ unsigned int pack4_fp8(float a, float b, float c, float d) {
    int v = 0;
    v = __builtin_amdgcn_cvt_pk_fp8_f32(a, b, v, false);   // bytes 0,1
    v = __builtin_amdgcn_cvt_pk_fp8_f32(c, d, v, true);    // bytes 2,3
    return (unsigned int)v;
}

__device__ __forceinline__ void unpack4_fp8(unsigned int v, float* out) {
    f32x2 lo = __builtin_amdgcn_cvt_pk_f32_fp8((int)v, false);
    f32x2 hi = __builtin_amdgcn_cvt_pk_f32_fp8((int)v, true);
    out[0] = lo[0]; out[1] = lo[1]; out[2] = hi[0]; out[3] = hi[1];
}

// accumulate 16 fp8 channels (one uint4), weighted
__device__ __forceinline__ void fma16_fp8(uint4 a, float w, float* acc) {
    unsigned int q[4] = {a.x, a.y, a.z, a.w};
#pragma unroll
    for (int k = 0; k < 4; ++k) {
        float f[4];
        unpack4_fp8(q[k], f);
#pragma unroll
        for (int j = 0; j < 4; ++j) acc[k * 4 + j] += f[j] * w;
    }
}

// accumulate 16 fp8 channels (one uint4), unweighted (rows pre-scaled by dinv[src])
__device__ __forceinline__ void add16_fp8(uint4 a, float* acc) {
    unsigned int q[4] = {a.x, a.y, a.z, a.w};
#pragma unroll
    for (int k = 0; k < 4; ++k) {
        float f[4];
        unpack4_fp8(q[k], f);
#pragma unroll
        for (int j = 0; j < 4; ++j) acc[k * 4 + j] += f[j];
    }
}

// ---------------- mega0: slotted fill + x->fp8 (unscaled) + gates + gstart + pack_w ----------------

__global__ __launch_bounds__(256) void mega0_kernel(
        const int* __restrict__ src, const int* __restrict__ dst,
        int* __restrict__ cnt, int* __restrict__ slots, int E,
        const float* __restrict__ x, unsigned int* __restrict__ x8,
        const float* __restrict__ tf, const float* __restrict__ Wg0,
        const float* __restrict__ Wg1, float* __restrict__ gates,
        const int* __restrict__ batch, int* __restrict__ gstart,
        const float* __restrict__ W0, const float* __restrict__ W1,
        __bf16* __restrict__ ph0, __bf16* __restrict__ ph1,
        int N, int G, int nFill, int nConv, int nGate) {
    int b = blockIdx.x;
    int t = threadIdx.x;

    if (b < nFill) {                        // XCD-sliced slotted fill, 8 edges/thread
        int slice = b & 7;
        int base = (b >> 3) * 2048 + t * 8;
        if (base < E) {
            if (base + 8 <= E) {
                int4 d0 = *(const int4*)(dst + base);
                int4 d1 = *(const int4*)(dst + base + 4);
                int dv[8] = {d0.x, d0.y, d0.z, d0.w, d1.x, d1.y, d1.z, d1.w};
#pragma unroll
                for (int k = 0; k < 8; ++k) {
                    int d = dv[k];
                    if (((d >> 6) & 7) != slice) continue;
                    int s = src[base + k];
                    int p = atomicAdd(&cnt[d], 1);
                    if (p < SLOTC) slots[(size_t)d * SLOTC + p] = s;
                }
            } else {
                for (int i = base; i < E; ++i) {
                    int d = dst[i];
                    if (((d >> 6) & 7) != slice) continue;
                    int s = src[i];
                    int p = atomicAdd(&cnt[d], 1);
                    if (p < SLOTC) slots[(size_t)d * SLOTC + p] = s;
                }
            }
        }
        return;
    }
    b -= nFill;
    if (b < nConv) {                        // x (fp32) -> fp8 unscaled, 16 elems/thread
        int i = b * 256 + t;
        int total16 = N * (HID / 16);
        if (i < total16) {
            const float4* xp = (const float4*)x + (size_t)i * 4;
            float4 v0 = xp[0], v1 = xp[1], v2 = xp[2], v3 = xp[3];
            uint4 o;
            o.x = pack4_fp8(v0.x, v0.y, v0.z, v0.w);
            o.y = pack4_fp8(v1.x, v1.y, v1.z, v1.w);
            o.z = pack4_fp8(v2.x, v2.y, v2.z, v2.w);
            o.w = pack4_fp8(v3.x, v3.y, v3.z, v3.w);
            ((uint4*)x8)[i] = o;
        }
        return;
    }
    b -= nConv;
    if (b < nGate) {                        // gate softmax for both layers
        int n = b * 256 + t;
        if (n >= N) return;
        float4 tv = *(const float4*)(tf + (size_t)n * TOP);
        const float* Wg[2] = {Wg0, Wg1};
#pragma unroll
        for (int l = 0; l < 2; ++l) {
            float lg[EXP];
#pragma unroll
            for (int e = 0; e < EXP; ++e) {
                const float* w = Wg[l] + e * TOP;
                lg[e] = (tv.x * w[0] + tv.y * w[1] + tv.z * w[2] + tv.w * w[3]) * (1.0f / 101.0f);
            }
            float m = fmaxf(lg[0], fmaxf(lg[1], lg[2]));
            float e0 = expf(lg[0] - m), e1 = expf(lg[1] - m), e2 = expf(lg[2] - m);
            float inv = 1.0f / (e0 + e1 + e2);
            gates[n * 6 + l * 3 + 0] = e0 * inv;
            gates[n * 6 + l * 3 + 1] = e1 * inv;
            gates[n * 6 + l * 3 + 2] = e2 * inv;
        }
        return;
    }
    b -= nGate;
    if (b == 0) {                           // gstart binary search
        int g = t;
        if (g > G) return;
        if (g == G) { gstart[G] = N; return; }
        int lo = 0, hi = N;
        while (lo < hi) {
            int mid = (lo + hi) >> 1;
            if (batch[mid] < g) lo = mid + 1; else hi = mid;
        }
        gstart[g] = lo;
        return;
    }
    b -= 1;
    // pack_w: 48 blocks x (4 jobs of 64 lanes)
    int job = b * 4 + (t >> 6);
    if (job >= 192) return;
    int l = t & 63;
    int layer = job / 96;
    int rem = job % 96;
    int e = rem / 32;
    int s = (rem % 32) / 4;
    int c = rem % 4;
    const float* W = layer ? W1 : W0;
    __bf16* ph = layer ? ph1 : ph0;
    size_t dstbase = (size_t)((((e * 8 + s) * 4 + c) * 64 + l)) * 8;
    int kbase = s * 16 + (l >> 5) * 8;
    int ncol = c * 32 + (l & 31);
#pragma unroll
    for (int j = 0; j < 8; ++j) {
        float w = W[(size_t)e * (HID * HID) + (size_t)(kbase + j) * HID + ncol];
        ph[dstbase + j] = (__bf16)w;
    }
}

// ---------------- fused aggregate + MFMA 3-expert GEMM + relu + gate ----------------
// WEIGHTED=true  (layer 1): input unscaled; per-edge w = rsqrt(cnt[s]+1), node-side *dn.
// WEIGHTED=false (layer 2): input pre-scaled by dinv[src]; pure adds, node-side *dn.
// phase 0: slot table (64x64 = 16KB) -> LDS. phase 1: 8 thr/node x 16 ch, 4-deep gathers.
// phase 2: MFMA 32x32x16, 8 waves x 1 tile. Epilogue writes h pre-scaled by dinv[row].

template <bool WEIGHTED>
__global__ __launch_bounds__(512, 4) void fused_layer_kernel(
        const unsigned char* __restrict__ h8in,
        const __bf16* __restrict__ wpkh,
        const float* __restrict__ bias, const float* __restrict__ gates, int gate_off,
        const int* __restrict__ cnt, const int* __restrict__ slots,
        unsigned char* __restrict__ hout8,
        const int* __restrict__ batch, float* __restrict__ pooled, int N) {
    __shared__ char lds[64 * OUT_STRIDE * 4];   // 33792 B: 17408 staging + 16384 slot cache
    int tid = threadIdx.x;
    int row0 = blockIdx.x * 64;

    // ---- phase 0: slot table -> LDS (coalesced; rows >= N carry garbage, never used) ----
    {
        uint4* sdst = (uint4*)(lds + SLOT_LDS_OFF);
        const uint4* ssrc = (const uint4*)(slots + (size_t)row0 * SLOTC);
        sdst[tid] = ssrc[tid];
        sdst[tid + 512] = ssrc[tid + 512];
    }
    __syncthreads();

    // ---- phase 1: aggregate into staging LDS ----
    {
        int r = tid >> 3;
        int part = tid & 7;                 // 16-channel slice
        int n = row0 + r;
        float acc[16];
#pragma unroll
        for (int j = 0; j < 16; ++j) acc[j] = 0.f;
        if (n < N) {
            const unsigned char* hb = h8in + part * 16;
            int degt = cnt[n];
            int deg = min(degt, SLOTC);
            float dn = rsqrtf((float)degt + 1.0f);
            // self contribution
            uint4 v = *(const uint4*)(hb + (size_t)n * HID);
            {
                unsigned int q[4] = {v.x, v.y, v.z, v.w};
                float sw = WEIGHTED ? dn : 1.0f;
#pragma unroll
                for (int k = 0; k < 4; ++k) {
                    float f[4];
                    unpack4_fp8(q[k], f);
#pragma unroll
                    for (int j = 0; j < 4; ++j) acc[k * 4 + j] = f[j] * sw;
                }
            }
            const int* sl = (const int*)(lds + SLOT_LDS_OFF) + r * SLOTC;
            int i = 0;
            for (; i + 4 <= deg; i += 4) {
                int4 sv = *(const int4*)(sl + i);          // LDS read, short latency
                uint4 a0 = *(const uint4*)(hb + (size_t)sv.x * HID);
                uint4 a1 = *(const uint4*)(hb + (size_t)sv.y * HID);
                uint4 a2 = *(const uint4*)(hb + (size_t)sv.z * HID);
                uint4 a3 = *(const uint4*)(hb + (size_t)sv.w * HID);
                if (WEIGHTED) {
                    int c0 = cnt[sv.x], c1 = cnt[sv.y], c2 = cnt[sv.z], c3 = cnt[sv.w];
                    fma16_fp8(a0, rsqrtf((float)c0 + 1.0f), acc);
                    fma16_fp8(a1, rsqrtf((float)c1 + 1.0f), acc);
                    fma16_fp8(a2, rsqrtf((float)c2 + 1.0f), acc);
                    fma16_fp8(a3, rsqrtf((float)c3 + 1.0f), acc);
                } else {
                    add16_fp8(a0, acc);
                    add16_fp8(a1, acc);
                    add16_fp8(a2, acc);
                    add16_fp8(a3, acc);
                }
            }
            for (; i < deg; ++i) {
                int s0 = sl[i];
                uint4 a0 = *(const uint4*)(hb + (size_t)s0 * HID);
                if (WEIGHTED) fma16_fp8(a0, rsqrtf((float)cnt[s0] + 1.0f), acc);
                else          add16_fp8(a0, acc);
            }
            // final node-side scale
#pragma unroll
            for (int j = 0; j < 16; ++j) acc[j] *= dn;
        }
        char* drow = lds + r * GLDS_STRIDE + part * 32;
        bf16x8 h0, h1;
#pragma unroll
        for (int j = 0; j < 8; ++j) { h0[j] = (__bf16)acc[j]; h1[j] = (__bf16)acc[8 + j]; }
        *(bf16x8*)drow = h0;
        *(bf16x8*)(drow + 16) = h1;
    }
    __syncthreads();

    // ---- phase 2: MFMA expert GEMM, 8 waves x 1 tile (rhalf x col-quarter) ----
    int lane = tid & 63;
    int wave = tid >> 6;                // 0..7
    int m = lane & 31;
    int g = lane >> 5;
    int rhalf = wave & 1;
    int cq = wave >> 1;                 // 0..3
    const char* arow = lds + (rhalf * 32 + m) * GLDS_STRIDE + g * 16;
    int rowbase = row0 + rhalf * 32 + 4 * g;

    float F[16];
#pragma unroll
    for (int r = 0; r < 16; ++r) F[r] = 0.f;

    for (int e = 0; e < EXP; ++e) {
        f32x16 acc;
#pragma unroll
        for (int r = 0; r < 16; ++r) acc[r] = 0.f;

#pragma unroll
        for (int s = 0; s < 8; ++s) {
            bf16x8 Ah = *(const bf16x8*)(arow + s * 32);
            bf16x8 Bh = *(const bf16x8*)(wpkh + (size_t)(((e * 8 + s) * 4 + cq) * 64 + lane) * 8);
            acc = __builtin_amdgcn_mfma_f32_32x32x16_bf16(Ah, Bh, acc, 0, 0, 0);
        }
        float gt[16];
#pragma unroll
        for (int r = 0; r < 16; ++r) {
            int rr = rowbase + (r & 3) + 8 * (r >> 2);
            gt[r] = (rr < N) ? gates[(size_t)rr * 6 + gate_off + e] : 0.f;
        }
        float bb = bias[e * HID + cq * 32 + m];
#pragma unroll
        for (int r = 0; r < 16; ++r)
            F[r] += gt[r] * fmaxf(acc[r] + bb, 0.f);
    }

    // ---- fragments -> LDS out-tile ----
    __syncthreads();
    float* lds32 = (float*)lds;
    {
        int colg = cq * 32 + m;
#pragma unroll
        for (int r = 0; r < 16; ++r) {
            int lr = rhalf * 32 + 4 * g + (r & 3) + 8 * (r >> 2);
            lds32[lr * OUT_STRIDE + colg] = F[r];
        }
    }
    __syncthreads();

    if (hout8) {
        // write h1 pre-scaled by dinv[row] so layer 2 aggregates without per-edge weights
#pragma unroll
        for (int it = 0; it < 4; ++it) {
            int id = tid + it * 512;
            int r = id >> 5;
            int c4 = id & 31;
            int gr = row0 + r;
            if (gr < N) {
                float dr = rsqrtf((float)cnt[gr] + 1.0f);
                const float* src = &lds32[r * OUT_STRIDE + c4 * 4];
                *(unsigned int*)(hout8 + (size_t)gr * HID + c4 * 4) =
                    pack4_fp8(src[0] * dr, src[1] * dr, src[2] * dr, src[3] * dr);
            }
        }
    }
    if (pooled) {
        int col = tid & 127;
        int rbase = (tid >> 7) * 16;
        int cur = -1;
        float acc = 0.f;
        for (int r = 0; r < 16; ++r) {
            int gr = row0 + rbase + r;
            if (gr >= N) break;
            int gb = batch[gr];
            if (gb != cur) {
                if (cur >= 0) atomicAdd(&pooled[cur * HID + col], acc);
                acc = 0.f;
                cur = gb;
            }
            acc += lds32[(rbase + r) * OUT_STRIDE + col];
        }
        if (cur >= 0) atomicAdd(&pooled[cur * HID + col], acc);
    }
}

// ---------------- final ----------------

__global__ __launch_bounds__(64) void final_kernel(const float* __restrict__ pooled,
                                                   const int* __restrict__ gstart,
                                                   const float* __restrict__ Wf,
                                                   const float* __restrict__ bf,
                                                   float* __restrict__ out) {
    __shared__ float ps[HID];
    int g = blockIdx.x;
    int o = threadIdx.x;
    float invc = 1.0f / fmaxf((float)(gstart[g + 1] - gstart[g]), 1.0f);
    ps[o] = pooled[g * HID + o] * invc;
    ps[o + 64] = pooled[g * HID + o + 64] * invc;
    __syncthreads();
    float acc = bf[o];
#pragma unroll 8
    for (int k = 0; k < HID; ++k) acc = fmaf(ps[k], Wf[k * OUTC + o], acc);
    out[g * OUTC + o] = acc;
}

// ---------------- launch ----------------

extern "C" void kernel_launch(void* const* d_in, const int* in_sizes, int n_in,
                              void* d_out, int out_size, void* d_ws, size_t ws_size,
                              hipStream_t stream) {
    const float* x   = (const float*)d_in[0];
    const float* tf  = (const float*)d_in[1];
    const int*   ei  = (const int*)d_in[2];
    const int*   bat = (const int*)d_in[3];
    const float* W0  = (const float*)d_in[4];
    const float* b0  = (const float*)d_in[5];
    const float* Wg0 = (const float*)d_in[6];
    const float* W1  = (const float*)d_in[7];
    const float* b1  = (const float*)d_in[8];
    const float* Wg1 = (const float*)d_in[9];
    const float* Wf  = (const float*)d_in[10];
    const float* bf  = (const float*)d_in[11];
    float* out = (float*)d_out;

    const int N = in_sizes[0] / HID;       // 50000
    const int E = in_sizes[2] / 2;         // 800000
    const int G = out_size / OUTC;         // 64

    char* p = (char*)d_ws;
    auto alloc = [&](size_t bytes) -> void* {
        void* r = (void*)p;
        p += (bytes + 255) & ~(size_t)255;
        return r;
    };
    // cnt and pooled adjacent -> single memset covers both
    int*           cnt    = (int*)alloc((size_t)N * 4);
    float*         pooled = (float*)alloc((size_t)G * HID * 4);
    int*           slots  = (int*)alloc((size_t)(N + 64) * SLOTC * 4); // +64 rows tail pad
    float*         gates  = (float*)alloc((size_t)N * 6 * 4);
    unsigned char* x8     = (unsigned char*)alloc((size_t)N * HID);   // layer-1 fp8 input (unscaled)
    unsigned char* h8b    = (unsigned char*)alloc((size_t)N * HID);   // layer-1 out (pre-scaled)
    int*           gstart = (int*)alloc((size_t)(G + 1) * 4);
    __bf16*        wpkh0  = (__bf16*)alloc((size_t)EXP * HID * HID * 2);
    __bf16*        wpkh1  = (__bf16*)alloc((size_t)EXP * HID * HID * 2);

    const int* src = ei;
    const int* dst = ei + E;

    size_t zlen = (size_t)((char*)pooled - (char*)cnt) + (size_t)G * HID * 4;
    hipMemsetAsync(cnt, 0, zlen, stream);

    const int nFill = ((E + 2047) / 2048) * 8;
    const int nConv = (N * (HID / 16) + 255) / 256;
    const int nGate = (N + 255) / 256;
    const int megaBlocks = nFill + nConv + nGate + 1 + 48;

    mega0_kernel<<<megaBlocks, 256, 0, stream>>>(src, dst, cnt, slots, E,
                                                 x, (unsigned int*)x8,
                                                 tf, Wg0, Wg1, gates,
                                                 bat, gstart,
                                                 W0, W1, wpkh0, wpkh1,
                                                 N, G, nFill, nConv, nGate);

    int gemm_blocks = (N + 63) / 64;

    // layer 1: weighted aggregation (per-edge rsqrt(cnt[s]+1)) + GEMM -> pre-scaled fp8 h
    fused_layer_kernel<true><<<gemm_blocks, 512, 0, stream>>>(x8, wpkh0, b0, gates, 0,
                                                              cnt, slots,
                                                              h8b, nullptr, nullptr, N);
    // layer 2: pure-add aggregation (input pre-scaled) + GEMM -> pooled
    fused_layer_kernel<false><<<gemm_blocks, 512, 0, stream>>>(h8b, wpkh1, b1, gates, 3,
                                                               cnt, slots,
                                                               nullptr, bat, pooled, N);

    final_kernel<<<G, 64, 0, stream>>>(pooled, gstart, Wf, bf, out);
}